// Round 5
// baseline (420.672 us; speedup 1.0000x reference)
//
#include <hip/hip_runtime.h>

// Problem constants (fixed by the reference setup)
#define T_ 4
#define N_ 100000
#define G_ 128
#define R_ 4
#define B_ 4096
#define K_ 32
#define I_ 128
#define BB 8           // b-rows per block

// out[t,b,i] = sum_r sum_g mean[t,r,b,g] * W[r,g,i]
// mean[t,r,b,g] = (sum_k mask * E[t, idx[t,r,b,k], g]) / max(sum_k mask, 1)
//
// Round-4 changes vs round-3 (both attack demand bytes — we measured
// traffic-bound: dur/FETCH invariant across occupancy 42->66%):
//  1. Mask compaction: only gather rows with mask=1 (halves gather demand).
//     Compaction rank via __ballot within each half-wave (row == half-wave).
//  2. t-phased grid-stride: 512 blocks loop over t, so the live random-access
//     footprint is one ~48MB t-slice (fits L3 easily) instead of ~2.5 slices.
__global__ __launch_bounds__(256) void static_influence_kernel(
    const float* __restrict__ E,     // [T,N,G]
    const float* __restrict__ W,     // [R,G,I]
    const int*   __restrict__ idx,   // [T,R,B,K]
    const int*   __restrict__ msk,   // [T,R,B,K] (0/1)
    float*       __restrict__ out)   // [T,B,I] flat
{
    const int tid = threadIdx.x;
    const int b0  = blockIdx.x * BB;

    __shared__ float mean_s[BB][G_];     // 4 KB
    __shared__ int   idxc_s[BB * K_];    // 1 KB compacted active ids
    __shared__ int   cnt_s[BB];

    const int wave = tid >> 6;
    const int lane = tid & 63;
    const int half = lane >> 5;
    const int gl   = lane & 31;          // gather g-chunk: g = gl*4 .. gl*4+3
    const int bbg  = 2 * wave + half;    // gather row owned by this half-wave

    const int iset = tid >> 7;           // matmul row-set: 0 or 1
    const int i    = tid & 127;          // output channel

    for (int t = 0; t < T_; ++t) {
        const float* __restrict__ Et = E + (size_t)t * N_ * G_;

        float acc0 = 0.f, acc1 = 0.f, acc2 = 0.f, acc3 = 0.f;

        for (int r = 0; r < R_; ++r) {
            // ---- stage + compact active indices (1 coalesced load each) ----
            {
                const int base = ((t * R_ + r) * B_ + b0) * K_;   // 256 ints
                const int  v   = idx[base + tid];
                const bool act = (msk[base + tid] != 0);
                const unsigned long long bal = __ballot(act);
                int rank = __popcll(bal & ((1ULL << lane) - 1));
                if (half) rank -= __popcll(bal & 0xFFFFFFFFULL);
                const int row = tid >> 5;                          // = bbg of this lane
                if (act) idxc_s[row * K_ + rank] = v;
                if ((lane & 31) == 0)
                    cnt_s[row] = __popcll((bal >> (half * 32)) & 0xFFFFFFFFULL);
            }
            __syncthreads();

            // ---- masked neighbor sum: only active rows, float4 per lane ----
            const int myc = cnt_s[bbg];
            float4 s4 = make_float4(0.f, 0.f, 0.f, 0.f);
#pragma unroll 4
            for (int k = 0; k < myc; ++k) {
                const int id = idxc_s[bbg * K_ + k];               // half-wave broadcast
                const float4 e4 = *reinterpret_cast<const float4*>(Et + (size_t)id * G_ + gl * 4);
                s4.x += e4.x;  s4.y += e4.y;  s4.z += e4.z;  s4.w += e4.w;
            }
            const float inv = 1.0f / fmaxf((float)myc, 1.0f);
            *reinterpret_cast<float4*>(&mean_s[bbg][gl * 4]) =
                make_float4(s4.x * inv, s4.y * inv, s4.z * inv, s4.w * inv);
            __syncthreads();

            // ---- acc[iset*4+j] += sum_g mean[bbm+j][g] * Wr[g][i] ----
            const float* __restrict__ Wr = W + r * G_ * I_;
            const int bbm = iset * 4;
#pragma unroll 2
            for (int g = 0; g < G_; g += 4) {
                const float w0 = Wr[(g + 0) * I_ + i];
                const float w1 = Wr[(g + 1) * I_ + i];
                const float w2 = Wr[(g + 2) * I_ + i];
                const float w3 = Wr[(g + 3) * I_ + i];
                const float4 m0 = *reinterpret_cast<const float4*>(&mean_s[bbm + 0][g]);
                const float4 m1 = *reinterpret_cast<const float4*>(&mean_s[bbm + 1][g]);
                const float4 m2 = *reinterpret_cast<const float4*>(&mean_s[bbm + 2][g]);
                const float4 m3 = *reinterpret_cast<const float4*>(&mean_s[bbm + 3][g]);
                acc0 += m0.x * w0 + m0.y * w1 + m0.z * w2 + m0.w * w3;
                acc1 += m1.x * w0 + m1.y * w1 + m1.z * w2 + m1.w * w3;
                acc2 += m2.x * w0 + m2.y * w1 + m2.z * w2 + m2.w * w3;
                acc3 += m3.x * w0 + m3.y * w1 + m3.z * w2 + m3.w * w3;
            }
            __syncthreads();
        }

        const size_t ob = ((size_t)t * B_ + b0 + iset * 4) * I_ + i;
        out[ob + 0 * I_] = acc0;
        out[ob + 1 * I_] = acc1;
        out[ob + 2 * I_] = acc2;
        out[ob + 3 * I_] = acc3;
    }
}

extern "C" void kernel_launch(void* const* d_in, const int* in_sizes, int n_in,
                              void* d_out, int out_size, void* d_ws, size_t ws_size,
                              hipStream_t stream) {
    const float* E   = (const float*)d_in[0];   // embeddings [T,N,G] f32
    const float* W   = (const float*)d_in[1];   // weights [R,G,I] f32
    const int*   idx = (const int*)d_in[2];     // neighbor_idx [T,R,B,K] i32
    const int*   msk = (const int*)d_in[3];     // neighbor_mask [T,R,B,K] i32
    float* out = (float*)d_out;                 // [T,B,I] f32 flat

    dim3 grid(B_ / BB);                          // 512 blocks, t-phased
    dim3 block(256);
    hipLaunchKernelGGL(static_influence_kernel, grid, block, 0, stream,
                       E, W, idx, msk, out);
}

// Round 7
// 370.712 us; speedup vs baseline: 1.1348x; 1.1348x over previous
//
#include <hip/hip_runtime.h>

// Problem constants (fixed by the reference setup)
#define T_ 4
#define N_ 100000
#define G_ 128
#define R_ 4
#define B_ 4096
#define K_ 32
#define I_ 128
#define BB 8           // b-rows per block

// out[t,b,i] = sum_r sum_g mean[t,r,b,g] * W[r,g,i]
// mean[t,r,b,g] = (sum_k mask * E[t, idx[t,r,b,k], g]) / max(sum_k mask, 1)
//
// Round-6: keep mask compaction (demand 1.07GB -> 0.54GB; FETCH proved
// proportional at 48% of demand), REVERT t-phasing (it cut occupancy
// 66% -> 23% and throughput scaled with occupancy -> concurrency-bound).
// Full 2048-block grid, t = blk/512 (sequential t phases, as round 3).
__global__ __launch_bounds__(256) void static_influence_kernel(
    const float* __restrict__ E,     // [T,N,G]
    const float* __restrict__ W,     // [R,G,I]
    const int*   __restrict__ idx,   // [T,R,B,K]
    const int*   __restrict__ msk,   // [T,R,B,K] (0/1)
    float*       __restrict__ out)   // [T,B,I] flat
{
    const int tid = threadIdx.x;
    const int blk = blockIdx.x;
    const int t   = blk / (B_ / BB);
    const int b0  = (blk % (B_ / BB)) * BB;

    __shared__ float mean_s[BB][G_];     // 4 KB
    __shared__ int   idxc_s[BB * K_];    // 1 KB compacted active ids
    __shared__ int   cnt_s[BB];

    const int wave = tid >> 6;
    const int lane = tid & 63;
    const int half = lane >> 5;
    const int gl   = lane & 31;          // gather g-chunk: g = gl*4 .. gl*4+3
    const int bbg  = 2 * wave + half;    // gather row owned by this half-wave

    const int iset = tid >> 7;           // matmul row-set: 0 or 1
    const int i    = tid & 127;          // output channel

    const float* __restrict__ Et = E + (size_t)t * N_ * G_;

    float acc0 = 0.f, acc1 = 0.f, acc2 = 0.f, acc3 = 0.f;

    for (int r = 0; r < R_; ++r) {
        // ---- stage + compact active indices (1 coalesced load each) ----
        {
            const int base = ((t * R_ + r) * B_ + b0) * K_;   // 256 ints
            const int  v   = idx[base + tid];
            const bool act = (msk[base + tid] != 0);
            const unsigned long long bal = __ballot(act);
            int rank = __popcll(bal & ((1ULL << lane) - 1));
            if (half) rank -= __popcll(bal & 0xFFFFFFFFULL);
            const int row = tid >> 5;                          // row owned by this half-wave
            if (act) idxc_s[row * K_ + rank] = v;
            if ((lane & 31) == 0)
                cnt_s[row] = __popcll((bal >> (half * 32)) & 0xFFFFFFFFULL);
        }
        __syncthreads();

        // ---- masked neighbor sum: only active rows, float4 per lane ----
        const int myc = cnt_s[bbg];
        float4 s4 = make_float4(0.f, 0.f, 0.f, 0.f);
#pragma unroll 8
        for (int k = 0; k < myc; ++k) {
            const int id = idxc_s[bbg * K_ + k];               // half-wave broadcast
            const float4 e4 = *reinterpret_cast<const float4*>(Et + (size_t)id * G_ + gl * 4);
            s4.x += e4.x;  s4.y += e4.y;  s4.z += e4.z;  s4.w += e4.w;
        }
        const float inv = 1.0f / fmaxf((float)myc, 1.0f);
        *reinterpret_cast<float4*>(&mean_s[bbg][gl * 4]) =
            make_float4(s4.x * inv, s4.y * inv, s4.z * inv, s4.w * inv);
        __syncthreads();

        // ---- acc[iset*4+j] += sum_g mean[bbm+j][g] * Wr[g][i] ----
        const float* __restrict__ Wr = W + r * G_ * I_;
        const int bbm = iset * 4;
#pragma unroll 2
        for (int g = 0; g < G_; g += 4) {
            const float w0 = Wr[(g + 0) * I_ + i];
            const float w1 = Wr[(g + 1) * I_ + i];
            const float w2 = Wr[(g + 2) * I_ + i];
            const float w3 = Wr[(g + 3) * I_ + i];
            const float4 m0 = *reinterpret_cast<const float4*>(&mean_s[bbm + 0][g]);
            const float4 m1 = *reinterpret_cast<const float4*>(&mean_s[bbm + 1][g]);
            const float4 m2 = *reinterpret_cast<const float4*>(&mean_s[bbm + 2][g]);
            const float4 m3 = *reinterpret_cast<const float4*>(&mean_s[bbm + 3][g]);
            acc0 += m0.x * w0 + m0.y * w1 + m0.z * w2 + m0.w * w3;
            acc1 += m1.x * w0 + m1.y * w1 + m1.z * w2 + m1.w * w3;
            acc2 += m2.x * w0 + m2.y * w1 + m2.z * w2 + m2.w * w3;
            acc3 += m3.x * w0 + m3.y * w1 + m3.z * w2 + m3.w * w3;
        }
        __syncthreads();
    }

    const size_t ob = ((size_t)t * B_ + b0 + iset * 4) * I_ + i;
    out[ob + 0 * I_] = acc0;
    out[ob + 1 * I_] = acc1;
    out[ob + 2 * I_] = acc2;
    out[ob + 3 * I_] = acc3;
}

extern "C" void kernel_launch(void* const* d_in, const int* in_sizes, int n_in,
                              void* d_out, int out_size, void* d_ws, size_t ws_size,
                              hipStream_t stream) {
    const float* E   = (const float*)d_in[0];   // embeddings [T,N,G] f32
    const float* W   = (const float*)d_in[1];   // weights [R,G,I] f32
    const int*   idx = (const int*)d_in[2];     // neighbor_idx [T,R,B,K] i32
    const int*   msk = (const int*)d_in[3];     // neighbor_mask [T,R,B,K] i32
    float* out = (float*)d_out;                 // [T,B,I] f32 flat

    dim3 grid(T_ * (B_ / BB));                   // 2048 blocks, full concurrency
    dim3 block(256);
    hipLaunchKernelGGL(static_influence_kernel, grid, block, 0, stream,
                       E, W, idx, msk, out);
}

// Round 10
// 366.345 us; speedup vs baseline: 1.1483x; 1.0119x over previous
//
#include <hip/hip_runtime.h>

// Problem constants (fixed by the reference setup)
#define T_ 4
#define N_ 100000
#define G_ 128
#define R_ 4
#define B_ 4096
#define K_ 32
#define I_ 128
#define BB 8           // b-rows per block

// out[t,b,i] = sum_r sum_g mean[t,r,b,g] * W[r,g,i]
// mean[t,r,b,g] = (sum_k mask * E[t, idx[t,r,b,k], g]) / max(sum_k mask, 1)
//
// Round-8: keep compaction (demand 1.07->0.54 GB) + full 2048-block grid,
// and restore deep per-wave MLP lost to the runtime-bound myc loop:
// process compacted ids in fixed chunks of 8 -> 8 independent
// global_load_dwordx4 in flight back-to-back; tail lanes reload
// idxc[myc-1] (same lanes fetched it last iter -> L1 hit, ~no HBM cost);
// accumulate predicated. r3 (32 indep loads) sustained 5.7 TB/s demand vs
// r7's 3.35 -> expect ~0.54GB / 5.7 TB/s ~ 94us gather.
__global__ __launch_bounds__(256) void static_influence_kernel(
    const float* __restrict__ E,     // [T,N,G]
    const float* __restrict__ W,     // [R,G,I]
    const int*   __restrict__ idx,   // [T,R,B,K]
    const int*   __restrict__ msk,   // [T,R,B,K] (0/1)
    float*       __restrict__ out)   // [T,B,I] flat
{
    const int tid = threadIdx.x;
    const int blk = blockIdx.x;
    const int t   = blk / (B_ / BB);
    const int b0  = (blk % (B_ / BB)) * BB;

    __shared__ float mean_s[BB][G_];     // 4 KB
    __shared__ int   idxc_s[BB * K_];    // 1 KB compacted active ids
    __shared__ int   cnt_s[BB];

    const int wave = tid >> 6;
    const int lane = tid & 63;
    const int half = lane >> 5;
    const int gl   = lane & 31;          // gather g-chunk: g = gl*4 .. gl*4+3
    const int bbg  = 2 * wave + half;    // gather row owned by this half-wave

    const int iset = tid >> 7;           // matmul row-set: 0 or 1
    const int i    = tid & 127;          // output channel

    const float* __restrict__ Et = E + (size_t)t * N_ * G_;

    float acc0 = 0.f, acc1 = 0.f, acc2 = 0.f, acc3 = 0.f;

    for (int r = 0; r < R_; ++r) {
        // ---- stage + compact active indices (1 coalesced load each) ----
        {
            const int base = ((t * R_ + r) * B_ + b0) * K_;   // 256 ints
            const int  v   = idx[base + tid];
            const bool act = (msk[base + tid] != 0);
            const unsigned long long bal = __ballot(act);
            int rank = __popcll(bal & ((1ULL << lane) - 1));
            if (half) rank -= __popcll(bal & 0xFFFFFFFFULL);
            const int row = tid >> 5;                          // row owned by this half-wave
            if (act) idxc_s[row * K_ + rank] = v;
            if ((lane & 31) == 0)
                cnt_s[row] = __popcll((bal >> (half * 32)) & 0xFFFFFFFFULL);
        }
        __syncthreads();

        // ---- masked neighbor sum: chunks of 8 independent loads ----
        const int myc    = cnt_s[bbg];
        const int rowbas = bbg * K_;
        float4 s4 = make_float4(0.f, 0.f, 0.f, 0.f);
        for (int k0 = 0; k0 < K_; k0 += 8) {
            if (k0 >= myc) break;
            int ids[8];
#pragma unroll
            for (int j = 0; j < 8; ++j) {
                int kk = k0 + j;
                kk = (kk < myc) ? kk : (myc - 1);              // tail: repeat last id (L1-hot)
                ids[j] = idxc_s[rowbas + kk];
            }
            float4 e[8];
#pragma unroll
            for (int j = 0; j < 8; ++j)
                e[j] = *reinterpret_cast<const float4*>(Et + (size_t)ids[j] * G_ + gl * 4);
#pragma unroll
            for (int j = 0; j < 8; ++j) {
                if (k0 + j < myc) {
                    s4.x += e[j].x;  s4.y += e[j].y;
                    s4.z += e[j].z;  s4.w += e[j].w;
                }
            }
        }
        const float inv = 1.0f / fmaxf((float)myc, 1.0f);
        *reinterpret_cast<float4*>(&mean_s[bbg][gl * 4]) =
            make_float4(s4.x * inv, s4.y * inv, s4.z * inv, s4.w * inv);
        __syncthreads();

        // ---- acc[iset*4+j] += sum_g mean[bbm+j][g] * Wr[g][i] ----
        const float* __restrict__ Wr = W + r * G_ * I_;
        const int bbm = iset * 4;
#pragma unroll 2
        for (int g = 0; g < G_; g += 4) {
            const float w0 = Wr[(g + 0) * I_ + i];
            const float w1 = Wr[(g + 1) * I_ + i];
            const float w2 = Wr[(g + 2) * I_ + i];
            const float w3 = Wr[(g + 3) * I_ + i];
            const float4 m0 = *reinterpret_cast<const float4*>(&mean_s[bbm + 0][g]);
            const float4 m1 = *reinterpret_cast<const float4*>(&mean_s[bbm + 1][g]);
            const float4 m2 = *reinterpret_cast<const float4*>(&mean_s[bbm + 2][g]);
            const float4 m3 = *reinterpret_cast<const float4*>(&mean_s[bbm + 3][g]);
            acc0 += m0.x * w0 + m0.y * w1 + m0.z * w2 + m0.w * w3;
            acc1 += m1.x * w0 + m1.y * w1 + m1.z * w2 + m1.w * w3;
            acc2 += m2.x * w0 + m2.y * w1 + m2.z * w2 + m2.w * w3;
            acc3 += m3.x * w0 + m3.y * w1 + m3.z * w2 + m3.w * w3;
        }
        __syncthreads();
    }

    const size_t ob = ((size_t)t * B_ + b0 + iset * 4) * I_ + i;
    out[ob + 0 * I_] = acc0;
    out[ob + 1 * I_] = acc1;
    out[ob + 2 * I_] = acc2;
    out[ob + 3 * I_] = acc3;
}

extern "C" void kernel_launch(void* const* d_in, const int* in_sizes, int n_in,
                              void* d_out, int out_size, void* d_ws, size_t ws_size,
                              hipStream_t stream) {
    const float* E   = (const float*)d_in[0];   // embeddings [T,N,G] f32
    const float* W   = (const float*)d_in[1];   // weights [R,G,I] f32
    const int*   idx = (const int*)d_in[2];     // neighbor_idx [T,R,B,K] i32
    const int*   msk = (const int*)d_in[3];     // neighbor_mask [T,R,B,K] i32
    float* out = (float*)d_out;                 // [T,B,I] f32 flat

    dim3 grid(T_ * (B_ / BB));                   // 2048 blocks, full concurrency
    dim3 block(256);
    hipLaunchKernelGGL(static_influence_kernel, grid, block, 0, stream,
                       E, W, idx, msk, out);
}

// Round 12
// 365.413 us; speedup vs baseline: 1.1512x; 1.0025x over previous
//
#include <hip/hip_runtime.h>

// Problem constants (fixed by the reference setup)
#define T_ 4
#define N_ 100000
#define G_ 128
#define R_ 4
#define B_ 4096
#define K_ 32
#define I_ 128
#define BB 8           // b-rows per block

// out[t,b,i] = sum_r sum_g mean[t,r,b,g] * W[r,g,i]
// mean[t,r,b,g] = (sum_k mask * E[t, idx[t,r,b,k], g]) / max(sum_k mask, 1)
//
// Round-11: pipeline gather(r+1) under matmul(r).
//  - idx stage + read are the SAME half-wave (row = tid>>5) -> no barrier needed
//  - count kept in-register from __ballot -> cnt_s removed
//  - mean_s double-buffered -> ONE __syncthreads per r (was 2)
//  - T14 async-split: chunk-0's 8 gather loads issued BEFORE matmul FMAs,
//    consumed after -> HBM/L3 latency hides under 512 FMAs.
__global__ __launch_bounds__(256) void static_influence_kernel(
    const float* __restrict__ E,     // [T,N,G]
    const float* __restrict__ W,     // [R,G,I]
    const int*   __restrict__ idx,   // [T,R,B,K]
    const int*   __restrict__ msk,   // [T,R,B,K] (0/1)
    float*       __restrict__ out)   // [T,B,I] flat
{
    const int tid = threadIdx.x;
    const int blk = blockIdx.x;
    const int t   = blk / (B_ / BB);
    const int b0  = (blk % (B_ / BB)) * BB;

    __shared__ float mean_s[2][BB][G_];   // 8 KB double-buffered
    __shared__ int   idxc_s[BB * K_];     // 1 KB compacted active ids

    const int lane = tid & 63;
    const int half = lane >> 5;
    const int gl   = lane & 31;           // gather g-chunk: g = gl*4 .. +3
    const int row  = tid >> 5;            // b-row owned by this half-wave

    const int iset = tid >> 7;            // matmul row-set: 0 or 1
    const int i    = tid & 127;           // output channel

    const float* __restrict__ Et = E + (size_t)t * N_ * G_;

    float acc0 = 0.f, acc1 = 0.f, acc2 = 0.f, acc3 = 0.f;

    // ---- stage idx+mask for r; all LDS traffic intra-half-wave (no barrier) ----
    auto stage_idx = [&](int r) -> int {
        const int base = ((t * R_ + r) * B_ + b0) * K_;
        const int  v   = idx[base + tid];
        const bool act = (msk[base + tid] != 0);
        const unsigned long long bal = __ballot(act);
        int rank = __popcll(bal & ((1ULL << lane) - 1));
        if (half) rank -= __popcll(bal & 0xFFFFFFFFULL);
        if (act) idxc_s[row * K_ + rank] = v;
        return (int)__popcll((bal >> (half * 32)) & 0xFFFFFFFFULL);
    };

    // ---- gather one chunk of 8 (clamped tail ids -> L1 hits) ----
    auto gather8 = [&](int k0, int myc, float4& s4) {
        int ids[8];
#pragma unroll
        for (int j = 0; j < 8; ++j) {
            int kk = k0 + j;
            kk = (kk < myc) ? kk : (myc - 1);
            ids[j] = idxc_s[row * K_ + kk];
        }
        float4 e[8];
#pragma unroll
        for (int j = 0; j < 8; ++j)
            e[j] = *reinterpret_cast<const float4*>(Et + (size_t)ids[j] * G_ + gl * 4);
#pragma unroll
        for (int j = 0; j < 8; ++j)
            if (k0 + j < myc) {
                s4.x += e[j].x;  s4.y += e[j].y;
                s4.z += e[j].z;  s4.w += e[j].w;
            }
    };

    // async-split state for chunk 0 of next relation (T14 issue-early/consume-late)
    float4 pe[8];

    auto issue8 = [&](int myc) {
        int ids[8];
#pragma unroll
        for (int j = 0; j < 8; ++j) {
            int kk = (j < myc) ? j : (myc - 1);
            ids[j] = idxc_s[row * K_ + kk];
        }
#pragma unroll
        for (int j = 0; j < 8; ++j)
            pe[j] = *reinterpret_cast<const float4*>(Et + (size_t)ids[j] * G_ + gl * 4);
    };
    auto consume8 = [&](int myc, float4& s4) {
#pragma unroll
        for (int j = 0; j < 8; ++j)
            if (j < myc) {
                s4.x += pe[j].x;  s4.y += pe[j].y;
                s4.z += pe[j].z;  s4.w += pe[j].w;
            }
    };

    // ---- prologue: full gather for r=0 into buffer 0 ----
    {
        const int myc = stage_idx(0);
        float4 s4 = make_float4(0.f, 0.f, 0.f, 0.f);
        for (int k0 = 0; k0 < K_; k0 += 8) {
            if (k0 >= myc) break;
            gather8(k0, myc, s4);
        }
        const float inv = 1.0f / fmaxf((float)myc, 1.0f);
        *reinterpret_cast<float4*>(&mean_s[0][row][gl * 4]) =
            make_float4(s4.x * inv, s4.y * inv, s4.z * inv, s4.w * inv);
    }

    for (int r = 0; r < R_; ++r) {
        __syncthreads();                       // publish mean_s[r&1] to all waves

        int nmyc = 0;
        if (r + 1 < R_) {
            nmyc = stage_idx(r + 1);
            if (nmyc > 0) issue8(nmyc);        // 8 loads in flight under the FMAs
        }

        // ---- matmul(r): acc[iset*4+j] += sum_g mean[r&1][bbm+j][g] * Wr[g][i] ----
        const float* __restrict__ Wr = W + r * G_ * I_;
        const int bbm = iset * 4;
        const float (*__restrict__ ms)[G_] = mean_s[r & 1];
#pragma unroll 2
        for (int g = 0; g < G_; g += 4) {
            const float w0 = Wr[(g + 0) * I_ + i];
            const float w1 = Wr[(g + 1) * I_ + i];
            const float w2 = Wr[(g + 2) * I_ + i];
            const float w3 = Wr[(g + 3) * I_ + i];
            const float4 m0 = *reinterpret_cast<const float4*>(&ms[bbm + 0][g]);
            const float4 m1 = *reinterpret_cast<const float4*>(&ms[bbm + 1][g]);
            const float4 m2 = *reinterpret_cast<const float4*>(&ms[bbm + 2][g]);
            const float4 m3 = *reinterpret_cast<const float4*>(&ms[bbm + 3][g]);
            acc0 += m0.x * w0 + m0.y * w1 + m0.z * w2 + m0.w * w3;
            acc1 += m1.x * w0 + m1.y * w1 + m1.z * w2 + m1.w * w3;
            acc2 += m2.x * w0 + m2.y * w1 + m2.z * w2 + m2.w * w3;
            acc3 += m3.x * w0 + m3.y * w1 + m3.z * w2 + m3.w * w3;
        }

        // ---- finish gather(r+1), write other mean buffer ----
        if (r + 1 < R_) {
            float4 n4 = make_float4(0.f, 0.f, 0.f, 0.f);
            if (nmyc > 0) consume8(nmyc, n4);
            for (int k0 = 8; k0 < K_; k0 += 8) {
                if (k0 >= nmyc) break;
                gather8(k0, nmyc, n4);
            }
            const float inv = 1.0f / fmaxf((float)nmyc, 1.0f);
            *reinterpret_cast<float4*>(&mean_s[(r + 1) & 1][row][gl * 4]) =
                make_float4(n4.x * inv, n4.y * inv, n4.z * inv, n4.w * inv);
        }
    }

    const size_t ob = ((size_t)t * B_ + b0 + iset * 4) * I_ + i;
    out[ob + 0 * I_] = acc0;
    out[ob + 1 * I_] = acc1;
    out[ob + 2 * I_] = acc2;
    out[ob + 3 * I_] = acc3;
}

extern "C" void kernel_launch(void* const* d_in, const int* in_sizes, int n_in,
                              void* d_out, int out_size, void* d_ws, size_t ws_size,
                              hipStream_t stream) {
    const float* E   = (const float*)d_in[0];   // embeddings [T,N,G] f32
    const float* W   = (const float*)d_in[1];   // weights [R,G,I] f32
    const int*   idx = (const int*)d_in[2];     // neighbor_idx [T,R,B,K] i32
    const int*   msk = (const int*)d_in[3];     // neighbor_mask [T,R,B,K] i32
    float* out = (float*)d_out;                 // [T,B,I] f32 flat

    dim3 grid(T_ * (B_ / BB));                   // 2048 blocks
    dim3 block(256);
    hipLaunchKernelGGL(static_influence_kernel, grid, block, 0, stream,
                       E, W, idx, msk, out);
}